// Round 2
// baseline (59.892 us; speedup 1.0000x reference)
//
#include <hip/hip_runtime.h>
#include <cmath>

#define NHEADS 8
#define HDIM 128
#define SPAN 24
#define U_ 16
#define W_ 128
#define C_ 151
#define HID 1024

typedef unsigned short ushort8v __attribute__((ext_vector_type(8)));
typedef __bf16 bf16x8 __attribute__((ext_vector_type(8)));
typedef float f32x4 __attribute__((ext_vector_type(4)));

__device__ inline unsigned short f2bf(float f) {
    union { float f; unsigned u; } v; v.f = f;
    unsigned r = v.u + 0x7FFFu + ((v.u >> 16) & 1u);
    return (unsigned short)(r >> 16);
}

// ---- kernel 1: partial column sums of pos_proj (64 blocks x 16 rows) ----
__global__ void k_partial(const float* __restrict__ pp, float* __restrict__ part) {
    const int t = threadIdx.x;            // 256 threads, each 4 cols (float4)
    const int row0 = blockIdx.x * 16;
    float4 s = make_float4(0.f, 0.f, 0.f, 0.f);
    #pragma unroll
    for (int i = 0; i < 16; ++i) {
        float4 v = *(const float4*)(pp + (size_t)(row0 + i) * HID + t * 4);
        s.x += v.x; s.y += v.y; s.z += v.z; s.w += v.w;
    }
    *(float4*)(part + (size_t)blockIdx.x * HID + t * 4) = s;
}

// ---- kernel 2: reduce partials, emit bf16 embedding table [24][1024] ----
struct SC { float s[SPAN]; float c[SPAN]; };

__global__ void k_emb(const float* __restrict__ part, unsigned short* __restrict__ emb, SC sc) {
    const int j = blockIdx.x * 256 + threadIdx.x;   // 0..1023
    float s1 = 0.f, s2 = 0.f;
    #pragma unroll 4
    for (int i = 0; i < 32; ++i) s1 += part[(size_t)i * HID + j];
    #pragma unroll 4
    for (int i = 32; i < 64; ++i) s2 += part[(size_t)i * HID + j];
    #pragma unroll
    for (int f = 0; f < SPAN; ++f)
        emb[(size_t)f * HID + j] = f2bf(sc.s[f] * s1 + sc.c[f] * s2);
}

// ---- main kernel: per-(b,u,n) fused GEMM 128x175x128 + relative shift ----
// LDS: K_ext bf16 [176 rows][128] XOR-swizzled; bd buffer [128][25] f32
// ALIASES the K region (K is dead after the MFMA loop) -> 45 056 B total,
// 3 blocks/CU instead of 2.
#define KEXT_BYTES (176 * 256)
#define BD_PITCH 25

__global__ __launch_bounds__(512, 4) void k_main(const float* __restrict__ q,
                                                 const float* __restrict__ k,
                                                 const unsigned short* __restrict__ emb,
                                                 float* __restrict__ out) {
    __shared__ __align__(16) char lds_raw[KEXT_BYTES];
    float* bd = (float*)lds_raw;   // alias — valid only after barrier #2

    const int bid = blockIdx.x;
    const int n = bid & 7;
    const int u = (bid >> 3) & 15;
    const int b = bid >> 7;

    const size_t qbase = ((size_t)(b * U_ + u) * W_) * HID + n * HDIM;
    const size_t kbase = ((size_t)(b * U_ + u) * C_) * HID + n * HDIM;
    const size_t obase = ((size_t)((b * NHEADS + n) * U_ + u)) * (W_ * C_);

    const int tid = threadIdx.x;
    const int lane = tid & 63;
    const int wave = tid >> 6;      // 0..7, owns rows 16*wave..+15
    const int w0 = wave * 16;
    const int lr = lane & 15;       // fragment row (A) / col (B)
    const int lk = lane >> 4;       // k-group 0..3

    // ---- prefetch Q rows into registers (overlaps with K staging below)
    const float* qrow = q + qbase + (size_t)(w0 + lr) * HID + lk * 8;
    float4 qa[8];
    #pragma unroll
    for (int kk = 0; kk < 4; ++kk) {
        qa[2 * kk]     = *(const float4*)(qrow + kk * 32);
        qa[2 * kk + 1] = *(const float4*)(qrow + kk * 32 + 4);
    }

    // ---- stage K_ext into LDS (convert fp32 -> bf16; rows 151..174 = emb; 175 = 0)
    for (int ui = tid; ui < 176 * 16; ui += 512) {
        const int r = ui >> 4, u16 = ui & 15;
        const int dst = r * 256 + ((u16 * 16) ^ ((r & 7) << 4));
        ushort8v val;
        if (r < C_) {
            const float* src = k + kbase + (size_t)r * HID + u16 * 8;
            float4 f0 = *(const float4*)src;
            float4 f1 = *(const float4*)(src + 4);
            val[0] = f2bf(f0.x); val[1] = f2bf(f0.y); val[2] = f2bf(f0.z); val[3] = f2bf(f0.w);
            val[4] = f2bf(f1.x); val[5] = f2bf(f1.y); val[6] = f2bf(f1.z); val[7] = f2bf(f1.w);
        } else if (r < 175) {
            val = *(const ushort8v*)(emb + (size_t)(r - C_) * HID + n * HDIM + u16 * 8);
        } else {
            val = (ushort8v)(unsigned short)0;
        }
        *(ushort8v*)(lds_raw + dst) = val;
    }
    __syncthreads();   // barrier #1: K tile ready

    f32x4 acc[11];
    #pragma unroll
    for (int j = 0; j < 11; ++j) acc[j] = (f32x4)(0.f);

    #pragma unroll
    for (int kk = 0; kk < 4; ++kk) {
        float4 a0 = qa[2 * kk];
        float4 a1 = qa[2 * kk + 1];
        ushort8v au;
        au[0] = f2bf(a0.x); au[1] = f2bf(a0.y); au[2] = f2bf(a0.z); au[3] = f2bf(a0.w);
        au[4] = f2bf(a1.x); au[5] = f2bf(a1.y); au[6] = f2bf(a1.z); au[7] = f2bf(a1.w);
        bf16x8 af = __builtin_bit_cast(bf16x8, au);
        #pragma unroll
        for (int j = 0; j < 11; ++j) {
            const int r = j * 16 + lr;
            const int byt = r * 256 + (((kk * 64) + (lk * 16)) ^ ((r & 7) << 4));
            bf16x8 bf = __builtin_bit_cast(bf16x8, *(const ushort8v*)(lds_raw + byt));
            acc[j] = __builtin_amdgcn_mfma_f32_16x16x32_bf16(af, bf, acc[j], 0, 0, 0);
        }
    }
    __syncthreads();   // barrier #2: everyone done READING K -> safe to reuse LDS

    // ---- write bd columns (S cols 151..174 -> f = 0..23) to LDS (aliased)
    {
        const int c9 = 144 + lr;              // tile 9: cols 144..159
        if (c9 >= C_) {
            const int f = c9 - C_;            // 0..8
            #pragma unroll
            for (int reg = 0; reg < 4; ++reg) {
                const int w = w0 + lk * 4 + reg;
                bd[w * BD_PITCH + f] = acc[9][reg];
            }
        }
        const int f10 = 9 + lr;               // tile 10: f = 9..24
        if (f10 < SPAN) {
            #pragma unroll
            for (int reg = 0; reg < 4; ++reg) {
                const int w = w0 + lk * 4 + reg;
                bd[w * BD_PITCH + f10] = acc[10][reg];
            }
        }
    }
    __syncthreads();   // barrier #3: bd ready

    // ---- final write: out[w][c] = ac + (0 <= c-w < 24 ? bd[w][c-w] : 0)
    #pragma unroll
    for (int j = 0; j < 10; ++j) {
        const int c = j * 16 + lr;
        if (c < C_) {
            #pragma unroll
            for (int reg = 0; reg < 4; ++reg) {
                const int w = w0 + lk * 4 + reg;
                float v = acc[j][reg];
                const int d = c - w;
                if (d >= 0 && d < SPAN) v += bd[w * BD_PITCH + d];
                out[obase + (size_t)w * C_ + c] = v;
            }
        }
    }
}

extern "C" void kernel_launch(void* const* d_in, const int* in_sizes, int n_in,
                              void* d_out, int out_size, void* d_ws, size_t ws_size,
                              hipStream_t stream) {
    const float* queries = (const float*)d_in[0];
    const float* keys    = (const float*)d_in[1];
    const float* posproj = (const float*)d_in[2];
    float* out = (float*)d_out;

    float* part = (float*)d_ws;                               // 64*1024 f32 = 256 KB
    unsigned short* emb = (unsigned short*)((char*)d_ws + 64 * HID * 4); // 24*1024 bf16

    SC sc;
    for (int f = 0; f < SPAN; ++f) {
        float p = (float)(11 - f);       // MAX_BACKWARD..-MAX_FORWARD
        sc.s[f] = sinf(p);
        sc.c[f] = cosf(p);
    }

    k_partial<<<64, 256, 0, stream>>>(posproj, part);
    k_emb<<<4, 256, 0, stream>>>(part, emb, sc);
    k_main<<<1024, 512, 0, stream>>>(queries, keys, emb, out);
}

// Round 3
// 59.225 us; speedup vs baseline: 1.0113x; 1.0113x over previous
//
#include <hip/hip_runtime.h>
#include <cmath>

#define NHEADS 8
#define HDIM 128
#define SPAN 24
#define U_ 16
#define W_ 128
#define C_ 151
#define HID 1024

typedef unsigned short ushort8v __attribute__((ext_vector_type(8)));
typedef __bf16 bf16x8 __attribute__((ext_vector_type(8)));
typedef float f32x4 __attribute__((ext_vector_type(4)));

__device__ inline unsigned short f2bf(float f) {
    union { float f; unsigned u; } v; v.f = f;
    unsigned r = v.u + 0x7FFFu + ((v.u >> 16) & 1u);
    return (unsigned short)(r >> 16);
}
__device__ inline float bf2f(unsigned short u) {
    union { unsigned u; float f; } v; v.u = ((unsigned)u) << 16;
    return v.f;
}

// ---- kernel 1: partial column sums of pos_proj (64 blocks x 16 rows) ----
__global__ void k_partial(const float* __restrict__ pp, float* __restrict__ part) {
    const int t = threadIdx.x;            // 256 threads, each 4 cols (float4)
    const int row0 = blockIdx.x * 16;
    float4 s = make_float4(0.f, 0.f, 0.f, 0.f);
    #pragma unroll
    for (int i = 0; i < 16; ++i) {
        float4 v = *(const float4*)(pp + (size_t)(row0 + i) * HID + t * 4);
        s.x += v.x; s.y += v.y; s.z += v.z; s.w += v.w;
    }
    *(float4*)(part + (size_t)blockIdx.x * HID + t * 4) = s;
}

// ---- kernel 2: reduce partials, emit bf16 embedding table [24][1024] ----
struct SC { float s[SPAN]; float c[SPAN]; };

__global__ void k_emb(const float* __restrict__ part, unsigned short* __restrict__ emb, SC sc) {
    const int j = blockIdx.x * 256 + threadIdx.x;   // 0..1023
    float s1 = 0.f, s2 = 0.f;
    #pragma unroll 4
    for (int i = 0; i < 32; ++i) s1 += part[(size_t)i * HID + j];
    #pragma unroll 4
    for (int i = 32; i < 64; ++i) s2 += part[(size_t)i * HID + j];
    #pragma unroll
    for (int f = 0; f < SPAN; ++f)
        emb[(size_t)f * HID + j] = f2bf(sc.s[f] * s1 + sc.c[f] * s2);
}

// ---- main kernel: per-(b,u,n) fused GEMM 128x175x128 + relative shift ----
// LDS: K_ext bf16 [176 rows][128] XOR-swizzled (45056 B)
//    + bd buffer bf16 [128 w][25] (6400 B)  -> 51456 B, 3 blocks/CU.
// ONE barrier total: bd is wave-private in w (each wave writes/reads only
// its own 16 rows), so no sync needed around the bd exchange.
#define KEXT_BYTES (176 * 256)
#define BD_PITCH 25

__global__ __launch_bounds__(512, 6) void k_main(const float* __restrict__ q,
                                                 const float* __restrict__ k,
                                                 const unsigned short* __restrict__ emb,
                                                 float* __restrict__ out) {
    __shared__ __align__(16) char lds_raw[KEXT_BYTES + W_ * BD_PITCH * 2];
    unsigned short* bd = (unsigned short*)(lds_raw + KEXT_BYTES);

    // XCD-chunked bijective remap: 1024 blocks = 8 XCDs x 128.
    // Logical blocks 8*bu..8*bu+7 (the 8 heads of one (b,u)) land on ONE XCD
    // so their shared Q/K cache lines live in one L2.
    const int bid = (blockIdx.x & 7) * 128 + (blockIdx.x >> 3);
    const int n = bid & 7;
    const int u = (bid >> 3) & 15;
    const int b = bid >> 7;

    const size_t qbase = ((size_t)(b * U_ + u) * W_) * HID + n * HDIM;
    const size_t kbase = ((size_t)(b * U_ + u) * C_) * HID + n * HDIM;
    const size_t obase = ((size_t)((b * NHEADS + n) * U_ + u)) * (W_ * C_);

    const int tid = threadIdx.x;
    const int lane = tid & 63;
    const int wave = tid >> 6;      // 0..7, owns rows 16*wave..+15
    const int w0 = wave * 16;
    const int lr = lane & 15;       // fragment row (A) / col (B)
    const int lk = lane >> 4;       // k-group 0..3

    // ---- stage K_ext into LDS (convert fp32 -> bf16; rows 151..174 = emb; 175 = 0)
    for (int ui = tid; ui < 176 * 16; ui += 512) {
        const int r = ui >> 4, u16 = ui & 15;
        const int dst = r * 256 + ((u16 * 16) ^ ((r & 7) << 4));
        ushort8v val;
        if (r < C_) {
            const float* src = k + kbase + (size_t)r * HID + u16 * 8;
            float4 f0 = *(const float4*)src;
            float4 f1 = *(const float4*)(src + 4);
            val[0] = f2bf(f0.x); val[1] = f2bf(f0.y); val[2] = f2bf(f0.z); val[3] = f2bf(f0.w);
            val[4] = f2bf(f1.x); val[5] = f2bf(f1.y); val[6] = f2bf(f1.z); val[7] = f2bf(f1.w);
        } else if (r < 175) {
            val = *(const ushort8v*)(emb + (size_t)(r - C_) * HID + n * HDIM + u16 * 8);
        } else {
            val = (ushort8v)(unsigned short)0;
        }
        *(ushort8v*)(lds_raw + dst) = val;
    }

    // ---- Q loads issued AFTER staging stores, BEFORE barrier: they drain
    // during the barrier wait.
    const float* qrow = q + qbase + (size_t)(w0 + lr) * HID + lk * 8;
    float4 qa[8];
    #pragma unroll
    for (int kk = 0; kk < 4; ++kk) {
        qa[2 * kk]     = *(const float4*)(qrow + kk * 32);
        qa[2 * kk + 1] = *(const float4*)(qrow + kk * 32 + 4);
    }
    bf16x8 qf[4];
    #pragma unroll
    for (int kk = 0; kk < 4; ++kk) {
        float4 a0 = qa[2 * kk];
        float4 a1 = qa[2 * kk + 1];
        ushort8v au;
        au[0] = f2bf(a0.x); au[1] = f2bf(a0.y); au[2] = f2bf(a0.z); au[3] = f2bf(a0.w);
        au[4] = f2bf(a1.x); au[5] = f2bf(a1.y); au[6] = f2bf(a1.z); au[7] = f2bf(a1.w);
        qf[kk] = __builtin_bit_cast(bf16x8, au);
    }
    __syncthreads();   // the only barrier: K tile ready

    f32x4 acc[11];
    #pragma unroll
    for (int j = 0; j < 11; ++j) acc[j] = (f32x4)(0.f);

    #pragma unroll
    for (int kk = 0; kk < 4; ++kk) {
        #pragma unroll
        for (int j = 0; j < 11; ++j) {
            const int r = j * 16 + lr;
            const int byt = r * 256 + (((kk * 64) + (lk * 16)) ^ ((r & 7) << 4));
            bf16x8 bf = __builtin_bit_cast(bf16x8, *(const ushort8v*)(lds_raw + byt));
            acc[j] = __builtin_amdgcn_mfma_f32_16x16x32_bf16(qf[kk], bf, acc[j], 0, 0, 0);
        }
    }

    // ---- write bd columns (S cols 151..174 -> f = 0..23) to wave-private LDS
    // rows; no barrier needed (same wave writes and reads its own w rows).
    {
        const int c9 = 144 + lr;              // tile 9: cols 144..159
        if (c9 >= C_) {
            const int f = c9 - C_;            // 0..8
            #pragma unroll
            for (int reg = 0; reg < 4; ++reg) {
                const int w = w0 + lk * 4 + reg;
                bd[w * BD_PITCH + f] = f2bf(acc[9][reg]);
            }
        }
        const int f10 = 9 + lr;               // tile 10: f = 9..24
        if (f10 < SPAN) {
            #pragma unroll
            for (int reg = 0; reg < 4; ++reg) {
                const int w = w0 + lk * 4 + reg;
                bd[w * BD_PITCH + f10] = f2bf(acc[10][reg]);
            }
        }
    }

    // ---- final write: out[w][c] = ac + (0 <= c-w < 24 ? bd[w][c-w] : 0)
    #pragma unroll
    for (int j = 0; j < 10; ++j) {
        const int c = j * 16 + lr;
        if (c < C_) {
            #pragma unroll
            for (int reg = 0; reg < 4; ++reg) {
                const int w = w0 + lk * 4 + reg;
                float v = acc[j][reg];
                const int d = c - w;
                if (d >= 0 && d < SPAN) v += bf2f(bd[w * BD_PITCH + d]);
                out[obase + (size_t)w * C_ + c] = v;
            }
        }
    }
}

extern "C" void kernel_launch(void* const* d_in, const int* in_sizes, int n_in,
                              void* d_out, int out_size, void* d_ws, size_t ws_size,
                              hipStream_t stream) {
    const float* queries = (const float*)d_in[0];
    const float* keys    = (const float*)d_in[1];
    const float* posproj = (const float*)d_in[2];
    float* out = (float*)d_out;

    float* part = (float*)d_ws;                               // 64*1024 f32 = 256 KB
    unsigned short* emb = (unsigned short*)((char*)d_ws + 64 * HID * 4); // 24*1024 bf16

    SC sc;
    for (int f = 0; f < SPAN; ++f) {
        float p = (float)(11 - f);       // MAX_BACKWARD..-MAX_FORWARD
        sc.s[f] = sinf(p);
        sc.c[f] = cosf(p);
    }

    k_partial<<<64, 256, 0, stream>>>(posproj, part);
    k_emb<<<4, 256, 0, stream>>>(part, emb, sc);
    k_main<<<1024, 512, 0, stream>>>(queries, keys, emb, out);
}

// Round 4
// 57.939 us; speedup vs baseline: 1.0337x; 1.0222x over previous
//
#include <hip/hip_runtime.h>
#include <cmath>

#define NHEADS 8
#define HDIM 128
#define SPAN 24
#define U_ 16
#define W_ 128
#define C_ 151
#define HID 1024

typedef unsigned short ushort8v __attribute__((ext_vector_type(8)));
typedef __bf16 bf16x8 __attribute__((ext_vector_type(8)));
typedef float f32x4 __attribute__((ext_vector_type(4)));

__device__ inline unsigned short f2bf(float f) {
    union { float f; unsigned u; } v; v.f = f;
    unsigned r = v.u + 0x7FFFu + ((v.u >> 16) & 1u);
    return (unsigned short)(r >> 16);
}
__device__ inline float bf2f(unsigned short u) {
    union { unsigned u; float f; } v; v.u = ((unsigned)u) << 16;
    return v.f;
}
__device__ inline ushort8v cvt8(float4 a, float4 b) {
    ushort8v v;
    v[0] = f2bf(a.x); v[1] = f2bf(a.y); v[2] = f2bf(a.z); v[3] = f2bf(a.w);
    v[4] = f2bf(b.x); v[5] = f2bf(b.y); v[6] = f2bf(b.z); v[7] = f2bf(b.w);
    return v;
}

// ---- kernel 1: partial column sums of pos_proj (64 blocks x 16 rows) ----
__global__ void k_partial(const float* __restrict__ pp, float* __restrict__ part) {
    const int t = threadIdx.x;
    const int row0 = blockIdx.x * 16;
    float4 s = make_float4(0.f, 0.f, 0.f, 0.f);
    #pragma unroll
    for (int i = 0; i < 16; ++i) {
        float4 v = *(const float4*)(pp + (size_t)(row0 + i) * HID + t * 4);
        s.x += v.x; s.y += v.y; s.z += v.z; s.w += v.w;
    }
    *(float4*)(part + (size_t)blockIdx.x * HID + t * 4) = s;
}

// ---- kernel 2: reduce partials, emit f32 embedding table [24][1024] ----
struct SC { float s[SPAN]; float c[SPAN]; };

__global__ void k_emb(const float* __restrict__ part, float* __restrict__ emb, SC sc) {
    const int j = blockIdx.x * 256 + threadIdx.x;   // 0..1023
    float s1 = 0.f, s2 = 0.f;
    #pragma unroll 4
    for (int i = 0; i < 32; ++i) s1 += part[(size_t)i * HID + j];
    #pragma unroll 4
    for (int i = 32; i < 64; ++i) s2 += part[(size_t)i * HID + j];
    #pragma unroll
    for (int f = 0; f < SPAN; ++f)
        emb[(size_t)f * HID + j] = sc.s[f] * s1 + sc.c[f] * s2;
}

// ---- main kernel: pipelined, 256 persistent blocks x 4 tiles ----
// LDS: 2 x K_ext bf16 [176][128] XOR-swizzled (2 x 45056) + bd bf16 [128][25]
// = 96512 B -> 1 block/CU, 2 waves/SIMD, big register budget for pipelining.
#define KB 45056
#define BD_PITCH 25
#define NITER 4

// staging slot map: ui = it*512+tid -> row r = ui>>4 (176 rows), u16 = ui&15.
// it 0..3: rows 0..127 (pure K). it 4: rows 128..159 (K or emb). tail
// (tid<256): rows 160..175 (emb or zero row 175).

#define STAGE_LOAD(TILE)                                                        \
    {                                                                           \
        const int n_ = (TILE) & 7;                                              \
        const int u_ = ((TILE) >> 3) & 15;                                      \
        const int b_ = (TILE) >> 7;                                             \
        const size_t kb_ = ((size_t)(b_ * U_ + u_) * C_) * HID + n_ * HDIM;     \
        _Pragma("unroll")                                                       \
        for (int it = 0; it < 4; ++it) {                                        \
            const int ui = it * 512 + tid;                                      \
            const int r = ui >> 4, u16 = ui & 15;                               \
            const float* src = k + kb_ + (size_t)r * HID + u16 * 8;             \
            pf0[it] = *(const float4*)src;                                      \
            pf1[it] = *(const float4*)(src + 4);                                \
        }                                                                       \
        {                                                                       \
            const int ui = 4 * 512 + tid;                                       \
            const int r = ui >> 4, u16 = ui & 15;                               \
            const float* src = (r < C_)                                         \
                ? (k + kb_ + (size_t)r * HID + u16 * 8)                         \
                : (embf + (size_t)(r - C_) * HID + n_ * HDIM + u16 * 8);        \
            pf0[4] = *(const float4*)src;                                       \
            pf1[4] = *(const float4*)(src + 4);                                 \
        }                                                                       \
        if (tid < 256) {                                                        \
            const int r = 160 + (tid >> 4), u16 = tid & 15;                     \
            if (r < 175) {                                                      \
                const float* src = embf + (size_t)(r - C_) * HID + n_ * HDIM + u16 * 8; \
                pt0 = *(const float4*)src;                                      \
                pt1 = *(const float4*)(src + 4);                                \
            }                                                                   \
        }                                                                       \
        const size_t qb_ = ((size_t)(b_ * U_ + u_) * W_) * HID + n_ * HDIM;     \
        const float* qrow_ = q + qb_ + (size_t)(w0 + lr) * HID + lk * 8;        \
        _Pragma("unroll")                                                       \
        for (int kk = 0; kk < 4; ++kk) {                                        \
            qpf[2 * kk]     = *(const float4*)(qrow_ + kk * 32);                \
            qpf[2 * kk + 1] = *(const float4*)(qrow_ + kk * 32 + 4);            \
        }                                                                       \
    }

#define STAGE_WRITE(BUF)                                                        \
    {                                                                           \
        _Pragma("unroll")                                                       \
        for (int it = 0; it < 5; ++it) {                                        \
            const int ui = it * 512 + tid;                                      \
            const int r = ui >> 4, u16 = ui & 15;                               \
            const int dst = r * 256 + ((u16 * 16) ^ ((r & 7) << 4));            \
            *(ushort8v*)((BUF) + dst) = cvt8(pf0[it], pf1[it]);                 \
        }                                                                       \
        if (tid < 256) {                                                        \
            const int r = 160 + (tid >> 4), u16 = tid & 15;                     \
            const int dst = r * 256 + ((u16 * 16) ^ ((r & 7) << 4));            \
            ushort8v v_;                                                        \
            if (r < 175) v_ = cvt8(pt0, pt1);                                   \
            else         v_ = (ushort8v)(unsigned short)0;                      \
            *(ushort8v*)((BUF) + dst) = v_;                                     \
        }                                                                       \
    }

__global__ __launch_bounds__(512, 2) void k_main(const float* __restrict__ q,
                                                 const float* __restrict__ k,
                                                 const float* __restrict__ embf,
                                                 float* __restrict__ out) {
    __shared__ __align__(16) char lds_raw[2 * KB + W_ * BD_PITCH * 2];
    unsigned short* bd = (unsigned short*)(lds_raw + 2 * KB);

    const int tid = threadIdx.x;
    const int lane = tid & 63;
    const int wave = tid >> 6;      // 0..7, owns Q rows 16*wave..+15
    const int w0 = wave * 16;
    const int lr = lane & 15;
    const int lk = lane >> 4;

    // XCD-chunked bijective remap: XCD x gets logical blocks x*32..x*32+31,
    // i.e. tiles x*128..x*128+127 contiguous per XCD.
    const int logical = (blockIdx.x & 7) * 32 + (blockIdx.x >> 3);
    const int tile0 = logical * NITER;

    float4 pf0[5], pf1[5], pt0, pt1, qpf[8];

    // ---- prologue: stage tile 0
    STAGE_LOAD(tile0);
    STAGE_WRITE(lds_raw);
    __syncthreads();

    for (int i = 0; i < NITER; ++i) {
        const int tile = tile0 + i;
        char* bufc = lds_raw + (i & 1) * KB;
        char* bufn = lds_raw + ((i & 1) ^ 1) * KB;

        // convert this tile's Q (loaded last iter) BEFORE qpf is overwritten
        bf16x8 qf[4];
        #pragma unroll
        for (int kk = 0; kk < 4; ++kk)
            qf[kk] = __builtin_bit_cast(bf16x8, cvt8(qpf[2 * kk], qpf[2 * kk + 1]));

        // issue next tile's global loads; they drain under the MFMA loop
        if (i + 1 < NITER) STAGE_LOAD(tile + 1);

        f32x4 acc[11];
        #pragma unroll
        for (int j = 0; j < 11; ++j) acc[j] = (f32x4)(0.f);

        #pragma unroll
        for (int kk = 0; kk < 4; ++kk) {
            #pragma unroll
            for (int j = 0; j < 11; ++j) {
                const int r = j * 16 + lr;
                const int byt = r * 256 + (((kk * 64) + (lk * 16)) ^ ((r & 7) << 4));
                bf16x8 bf = __builtin_bit_cast(bf16x8, *(const ushort8v*)(bufc + byt));
                acc[j] = __builtin_amdgcn_mfma_f32_16x16x32_bf16(qf[kk], bf, acc[j], 0, 0, 0);
            }
        }

        // write next tile into the other LDS buffer (overlaps with stores below)
        if (i + 1 < NITER) STAGE_WRITE(bufn);

        // ---- bd exchange (wave-private rows -> no barrier needed)
        {
            const int c9 = 144 + lr;              // tile 9: cols 144..159
            if (c9 >= C_) {
                const int f = c9 - C_;            // 0..8
                #pragma unroll
                for (int reg = 0; reg < 4; ++reg) {
                    const int w = w0 + lk * 4 + reg;
                    bd[w * BD_PITCH + f] = f2bf(acc[9][reg]);
                }
            }
            const int f10 = 9 + lr;               // tile 10: f = 9..23
            if (f10 < SPAN) {
                #pragma unroll
                for (int reg = 0; reg < 4; ++reg) {
                    const int w = w0 + lk * 4 + reg;
                    bd[w * BD_PITCH + f10] = f2bf(acc[10][reg]);
                }
            }
        }

        // ---- final write: out[w][c] = ac + (0 <= c-w < 24 ? bd[w][c-w] : 0)
        {
            const int n_ = tile & 7;
            const int u_ = (tile >> 3) & 15;
            const int b_ = tile >> 7;
            const size_t ob_ = ((size_t)((b_ * NHEADS + n_) * U_ + u_)) * (W_ * C_);
            #pragma unroll
            for (int j = 0; j < 10; ++j) {
                const int c = j * 16 + lr;
                if (c < C_) {
                    #pragma unroll
                    for (int reg = 0; reg < 4; ++reg) {
                        const int w = w0 + lk * 4 + reg;
                        float v = acc[j][reg];
                        const int d = c - w;
                        if (d >= 0 && d < SPAN) v += bf2f(bd[w * BD_PITCH + d]);
                        out[ob_ + (size_t)w * C_ + c] = v;
                    }
                }
            }
        }

        __syncthreads();   // all reads of bufc done; bufn fully written
    }
}

extern "C" void kernel_launch(void* const* d_in, const int* in_sizes, int n_in,
                              void* d_out, int out_size, void* d_ws, size_t ws_size,
                              hipStream_t stream) {
    const float* queries = (const float*)d_in[0];
    const float* keys    = (const float*)d_in[1];
    const float* posproj = (const float*)d_in[2];
    float* out = (float*)d_out;

    float* part = (float*)d_ws;                                // 64*1024 f32 = 256 KB
    float* embf = (float*)((char*)d_ws + 64 * HID * 4);        // 24*1024 f32 = 96 KB

    SC sc;
    for (int f = 0; f < SPAN; ++f) {
        float p = (float)(11 - f);       // MAX_BACKWARD..-MAX_FORWARD
        sc.s[f] = sinf(p);
        sc.c[f] = cosf(p);
    }

    k_partial<<<64, 256, 0, stream>>>(posproj, part);
    k_emb<<<4, 256, 0, stream>>>(part, embf, sc);
    k_main<<<256, 512, 0, stream>>>(queries, keys, embf, out);
}

// Round 5
// 57.454 us; speedup vs baseline: 1.0424x; 1.0085x over previous
//
#include <hip/hip_runtime.h>
#include <cmath>

#define NHEADS 8
#define HDIM 128
#define SPAN 24
#define U_ 16
#define W_ 128
#define C_ 151
#define HID 1024

typedef unsigned short ushort8v __attribute__((ext_vector_type(8)));
typedef __bf16 bf16x8 __attribute__((ext_vector_type(8)));
typedef float f32x4 __attribute__((ext_vector_type(4)));

__device__ inline unsigned short f2bf(float f) {
    union { float f; unsigned u; } v; v.f = f;
    unsigned r = v.u + 0x7FFFu + ((v.u >> 16) & 1u);
    return (unsigned short)(r >> 16);
}
__device__ inline float bf2f(unsigned short u) {
    union { unsigned u; float f; } v; v.u = ((unsigned)u) << 16;
    return v.f;
}
__device__ inline ushort8v cvt8(float4 a, float4 b) {
    ushort8v v;
    v[0] = f2bf(a.x); v[1] = f2bf(a.y); v[2] = f2bf(a.z); v[3] = f2bf(a.w);
    v[4] = f2bf(b.x); v[5] = f2bf(b.y); v[6] = f2bf(b.z); v[7] = f2bf(b.w);
    return v;
}

// ---- kernel 1: partial column sums of pos_proj (64 blocks x 16 rows) ----
__global__ void k_partial(const float* __restrict__ pp, float* __restrict__ part) {
    const int t = threadIdx.x;
    const int row0 = blockIdx.x * 16;
    float4 s = make_float4(0.f, 0.f, 0.f, 0.f);
    #pragma unroll
    for (int i = 0; i < 16; ++i) {
        float4 v = *(const float4*)(pp + (size_t)(row0 + i) * HID + t * 4);
        s.x += v.x; s.y += v.y; s.z += v.z; s.w += v.w;
    }
    *(float4*)(part + (size_t)blockIdx.x * HID + t * 4) = s;
}

// ---- kernel 2: reduce partials, emit f32 embedding table [24][1024] ----
struct SC { float s[SPAN]; float c[SPAN]; };

__global__ void k_emb(const float* __restrict__ part, float* __restrict__ emb, SC sc) {
    const int j = blockIdx.x * 256 + threadIdx.x;   // 0..1023
    float s1 = 0.f, s2 = 0.f;
    #pragma unroll 4
    for (int i = 0; i < 32; ++i) s1 += part[(size_t)i * HID + j];
    #pragma unroll 4
    for (int i = 32; i < 64; ++i) s2 += part[(size_t)i * HID + j];
    #pragma unroll
    for (int f = 0; f < SPAN; ++f)
        emb[(size_t)f * HID + j] = sc.s[f] * s1 + sc.c[f] * s2;
}

// ---- main kernel: per-(b,u,n) fused GEMM 128x175x128 + relative shift ----
// Single K buffer (45056 B) + bd (6400 B) = 51456 B LDS; VGPR capped at 128
// via __launch_bounds__(512,4) -> 2 blocks/CU co-resident at staggered
// phases. All 20 staging loads are issued into registers with NO dependent
// VALU between them (max MLP); converts/ds_writes happen afterwards.
#define KEXT_BYTES (176 * 256)
#define BD_PITCH 25

__global__ __launch_bounds__(512, 4) void k_main(const float* __restrict__ q,
                                                 const float* __restrict__ k,
                                                 const float* __restrict__ embf,
                                                 float* __restrict__ out) {
    __shared__ __align__(16) char lds_raw[KEXT_BYTES + W_ * BD_PITCH * 2];
    unsigned short* bd = (unsigned short*)(lds_raw + KEXT_BYTES);

    const int bid = blockIdx.x;
    const int n = bid & 7;
    const int u = (bid >> 3) & 15;
    const int b = bid >> 7;

    const size_t qbase = ((size_t)(b * U_ + u) * W_) * HID + n * HDIM;
    const size_t kbase = ((size_t)(b * U_ + u) * C_) * HID + n * HDIM;
    const size_t obase = ((size_t)((b * NHEADS + n) * U_ + u)) * (W_ * C_);

    const int tid = threadIdx.x;
    const int lane = tid & 63;
    const int wave = tid >> 6;      // 0..7, owns Q rows 16*wave..+15
    const int w0 = wave * 16;
    const int lr = lane & 15;
    const int lk = lane >> 4;

    // ---- phase 1: issue ALL global loads back-to-back (no dependent VALU)
    // K_ext slots: ui = it*512 + tid -> row r = ui>>4, 16B-pair u16 = ui&15.
    float4 pf0[5], pf1[5], pt0, pt1;
    #pragma unroll
    for (int it = 0; it < 5; ++it) {
        const int ui = it * 512 + tid;
        const int r = ui >> 4, u16 = ui & 15;
        const float* src = (r < C_)
            ? (k + kbase + (size_t)r * HID + u16 * 8)
            : (embf + (size_t)(r - C_) * HID + n * HDIM + u16 * 8);
        pf0[it] = *(const float4*)src;
        pf1[it] = *(const float4*)(src + 4);
    }
    if (tid < 256) {
        const int r = 160 + (tid >> 4), u16 = tid & 15;
        if (r < 175) {
            const float* src = embf + (size_t)(r - C_) * HID + n * HDIM + u16 * 8;
            pt0 = *(const float4*)src;
            pt1 = *(const float4*)(src + 4);
        }
    }
    const float* qrow = q + qbase + (size_t)(w0 + lr) * HID + lk * 8;
    float4 qpf[8];
    #pragma unroll
    for (int kk = 0; kk < 4; ++kk) {
        qpf[2 * kk]     = *(const float4*)(qrow + kk * 32);
        qpf[2 * kk + 1] = *(const float4*)(qrow + kk * 32 + 4);
    }

    // ---- phase 2: convert + stage into LDS (XOR-swizzled rows)
    #pragma unroll
    for (int it = 0; it < 5; ++it) {
        const int ui = it * 512 + tid;
        const int r = ui >> 4, u16 = ui & 15;
        const int dst = r * 256 + ((u16 * 16) ^ ((r & 7) << 4));
        *(ushort8v*)(lds_raw + dst) = cvt8(pf0[it], pf1[it]);
    }
    if (tid < 256) {
        const int r = 160 + (tid >> 4), u16 = tid & 15;
        const int dst = r * 256 + ((u16 * 16) ^ ((r & 7) << 4));
        ushort8v v_;
        if (r < 175) v_ = cvt8(pt0, pt1);
        else         v_ = (ushort8v)(unsigned short)0;
        *(ushort8v*)(lds_raw + dst) = v_;
    }

    // Q converts overlap the barrier wait
    bf16x8 qf[4];
    #pragma unroll
    for (int kk = 0; kk < 4; ++kk)
        qf[kk] = __builtin_bit_cast(bf16x8, cvt8(qpf[2 * kk], qpf[2 * kk + 1]));

    __syncthreads();   // the only barrier: K tile ready

    // ---- phase 3: MFMA
    f32x4 acc[11];
    #pragma unroll
    for (int j = 0; j < 11; ++j) acc[j] = (f32x4)(0.f);

    #pragma unroll
    for (int kk = 0; kk < 4; ++kk) {
        #pragma unroll
        for (int j = 0; j < 11; ++j) {
            const int r = j * 16 + lr;
            const int byt = r * 256 + (((kk * 64) + (lk * 16)) ^ ((r & 7) << 4));
            bf16x8 bf = __builtin_bit_cast(bf16x8, *(const ushort8v*)(lds_raw + byt));
            acc[j] = __builtin_amdgcn_mfma_f32_16x16x32_bf16(qf[kk], bf, acc[j], 0, 0, 0);
        }
    }

    // ---- bd exchange (wave-private rows -> no barrier needed)
    {
        const int c9 = 144 + lr;              // tile 9: cols 144..159
        if (c9 >= C_) {
            const int f = c9 - C_;            // 0..8
            #pragma unroll
            for (int reg = 0; reg < 4; ++reg) {
                const int w = w0 + lk * 4 + reg;
                bd[w * BD_PITCH + f] = f2bf(acc[9][reg]);
            }
        }
        const int f10 = 9 + lr;               // tile 10: f = 9..23
        if (f10 < SPAN) {
            #pragma unroll
            for (int reg = 0; reg < 4; ++reg) {
                const int w = w0 + lk * 4 + reg;
                bd[w * BD_PITCH + f10] = f2bf(acc[10][reg]);
            }
        }
    }

    // ---- final write: out[w][c] = ac + (0 <= c-w < 24 ? bd[w][c-w] : 0)
    #pragma unroll
    for (int j = 0; j < 10; ++j) {
        const int c = j * 16 + lr;
        if (c < C_) {
            #pragma unroll
            for (int reg = 0; reg < 4; ++reg) {
                const int w = w0 + lk * 4 + reg;
                float v = acc[j][reg];
                const int d = c - w;
                if (d >= 0 && d < SPAN) v += bf2f(bd[w * BD_PITCH + d]);
                out[obase + (size_t)w * C_ + c] = v;
            }
        }
    }
}

extern "C" void kernel_launch(void* const* d_in, const int* in_sizes, int n_in,
                              void* d_out, int out_size, void* d_ws, size_t ws_size,
                              hipStream_t stream) {
    const float* queries = (const float*)d_in[0];
    const float* keys    = (const float*)d_in[1];
    const float* posproj = (const float*)d_in[2];
    float* out = (float*)d_out;

    float* part = (float*)d_ws;                                // 64*1024 f32 = 256 KB
    float* embf = (float*)((char*)d_ws + 64 * HID * 4);        // 24*1024 f32 = 96 KB

    SC sc;
    for (int f = 0; f < SPAN; ++f) {
        float p = (float)(11 - f);       // MAX_BACKWARD..-MAX_FORWARD
        sc.s[f] = sinf(p);
        sc.c[f] = cosf(p);
    }

    k_partial<<<64, 256, 0, stream>>>(posproj, part);
    k_emb<<<4, 256, 0, stream>>>(part, embf, sc);
    k_main<<<1024, 512, 0, stream>>>(queries, keys, embf, out);
}

// Round 6
// 50.901 us; speedup vs baseline: 1.1766x; 1.1287x over previous
//
#include <hip/hip_runtime.h>
#include <cmath>

#define NHEADS 8
#define HDIM 128
#define SPAN 24
#define U_ 16
#define W_ 128
#define C_ 151
#define HID 1024

typedef unsigned short ushort8v __attribute__((ext_vector_type(8)));
typedef unsigned short ushort4v __attribute__((ext_vector_type(4)));
typedef __bf16 bf16x8 __attribute__((ext_vector_type(8)));
typedef float f32x4 __attribute__((ext_vector_type(4)));

__device__ inline unsigned short f2bf(float f) {
    union { float f; unsigned u; } v; v.f = f;
    unsigned r = v.u + 0x7FFFu + ((v.u >> 16) & 1u);
    return (unsigned short)(r >> 16);
}
__device__ inline float bf2f(unsigned short u) {
    union { unsigned u; float f; } v; v.u = ((unsigned)u) << 16;
    return v.f;
}
__device__ inline ushort8v cvt8(float4 a, float4 b) {
    ushort8v v;
    v[0] = f2bf(a.x); v[1] = f2bf(a.y); v[2] = f2bf(a.z); v[3] = f2bf(a.w);
    v[4] = f2bf(b.x); v[5] = f2bf(b.y); v[6] = f2bf(b.z); v[7] = f2bf(b.w);
    return v;
}

// ---- kernel 1: partial column sums of pos_proj (64 blocks x 16 rows) ----
// part[bi][j] = sum of pos_proj rows bi*16..bi*16+15, col j. Deterministic.
__global__ void k_partial(const float* __restrict__ pp, float* __restrict__ part) {
    const int t = threadIdx.x;
    const int row0 = blockIdx.x * 16;
    float4 s = make_float4(0.f, 0.f, 0.f, 0.f);
    #pragma unroll
    for (int i = 0; i < 16; ++i) {
        float4 v = *(const float4*)(pp + (size_t)(row0 + i) * HID + t * 4);
        s.x += v.x; s.y += v.y; s.z += v.z; s.w += v.w;
    }
    *(float4*)(part + (size_t)blockIdx.x * HID + t * 4) = s;
}

struct SC { float s[SPAN]; float c[SPAN]; };

// ---- main kernel: per-(b,u,n) fused GEMM 128x175x128 + relative shift ----
// emb rows are synthesized IN-BLOCK from the 64-partial table (no k_emb
// kernel): redp (bf16 [16][128], 4KB) + s12 (f32 [2][128], 1KB) alias the
// bd region (6400B, dead until after MFMA). LDS total 51456B -> 3 blocks/CU.
#define KEXT_BYTES (176 * 256)
#define BD_PITCH 25
#define AUX_OFF KEXT_BYTES
#define S12_OFF (KEXT_BYTES + 4096)

__global__ __launch_bounds__(512, 4) void k_main(const float* __restrict__ q,
                                                 const float* __restrict__ k,
                                                 const float* __restrict__ part,
                                                 float* __restrict__ out, SC sc) {
    __shared__ __align__(16) char lds_raw[KEXT_BYTES + W_ * BD_PITCH * 2];
    unsigned short* bd = (unsigned short*)(lds_raw + KEXT_BYTES);  // alias of redp/s12

    const int bid = blockIdx.x;
    const int n = bid & 7;
    const int u = (bid >> 3) & 15;
    const int b = bid >> 7;

    const size_t qbase = ((size_t)(b * U_ + u) * W_) * HID + n * HDIM;
    const size_t kbase = ((size_t)(b * U_ + u) * C_) * HID + n * HDIM;
    const size_t obase = ((size_t)((b * NHEADS + n) * U_ + u)) * (W_ * C_);

    const int tid = threadIdx.x;
    const int lane = tid & 63;
    const int wave = tid >> 6;      // 0..7, owns Q rows 16*wave..+15
    const int w0 = wave * 16;
    const int lr = lane & 15;
    const int lk = lane >> 4;

    // ---- phase 1: issue ALL global loads back-to-back
    float4 pf0[5], pf1[5];
    #pragma unroll
    for (int it = 0; it < 5; ++it) {
        const int ui = it * 512 + tid;
        const int r = ui >> 4, u16 = ui & 15;
        if (r < C_) {
            const float* src = k + kbase + (size_t)r * HID + u16 * 8;
            pf0[it] = *(const float4*)src;
            pf1[it] = *(const float4*)(src + 4);
        }
    }
    // partial-table loads: thread t covers 4 partial-rows x 4 cols of the
    // head's 128-col slice.  c4 = col-group, rg = partial-row group.
    const int c4 = tid & 31, rg = tid >> 5;   // c4 0..31, rg 0..15
    float4 pp4[4];
    #pragma unroll
    for (int i = 0; i < 4; ++i)
        pp4[i] = *(const float4*)(part + (size_t)(rg * 4 + i) * HID + n * HDIM + c4 * 4);
    // Q loads
    const float* qrow = q + qbase + (size_t)(w0 + lr) * HID + lk * 8;
    float4 qpf[8];
    #pragma unroll
    for (int kk = 0; kk < 4; ++kk) {
        qpf[2 * kk]     = *(const float4*)(qrow + kk * 32);
        qpf[2 * kk + 1] = *(const float4*)(qrow + kk * 32 + 4);
    }

    // ---- phase 2a: stage K rows into LDS (XOR-swizzled); store redp partials
    #pragma unroll
    for (int it = 0; it < 5; ++it) {
        const int ui = it * 512 + tid;
        const int r = ui >> 4, u16 = ui & 15;
        if (r < C_) {
            const int dst = r * 256 + ((u16 * 16) ^ ((r & 7) << 4));
            *(ushort8v*)(lds_raw + dst) = cvt8(pf0[it], pf1[it]);
        }
    }
    {
        float4 rs;
        rs.x = pp4[0].x + pp4[1].x + pp4[2].x + pp4[3].x;
        rs.y = pp4[0].y + pp4[1].y + pp4[2].y + pp4[3].y;
        rs.z = pp4[0].z + pp4[1].z + pp4[2].z + pp4[3].z;
        rs.w = pp4[0].w + pp4[1].w + pp4[2].w + pp4[3].w;
        ushort4v rb;
        rb[0] = f2bf(rs.x); rb[1] = f2bf(rs.y); rb[2] = f2bf(rs.z); rb[3] = f2bf(rs.w);
        // redp[rg][c4*4..+3] bf16 at AUX_OFF: addr = rg*256 + c4*8 (8B store)
        *(ushort4v*)(lds_raw + AUX_OFF + rg * 256 + c4 * 8) = rb;
    }
    __syncthreads();   // barrier A: redp ready

    // ---- phase 2b: reduce redp -> s12 (S1 = partial rows 0..31, S2 = 32..63)
    if (tid < 256) {
        const int col = tid & 127, half = tid >> 7;
        float s = 0.f;
        #pragma unroll
        for (int g = 0; g < 8; ++g)
            s += bf2f(*(const unsigned short*)(lds_raw + AUX_OFF + (half * 8 + g) * 256 + col * 2));
        *(float*)(lds_raw + S12_OFF + (half * 128 + col) * 4) = s;
    }
    __syncthreads();   // barrier B: s12 ready

    // ---- phase 2c: synthesize emb rows 151..174 into K_ext; zero row 175
    if (tid < 384) {
        const int f = tid >> 4, u16 = tid & 15;   // f 0..23
        const int r = C_ + f;
        const float sf = sc.s[f], cf = sc.c[f];
        ushort8v v;
        #pragma unroll
        for (int e = 0; e < 8; ++e) {
            const int col = u16 * 8 + e;
            const float S1 = *(const float*)(lds_raw + S12_OFF + col * 4);
            const float S2 = *(const float*)(lds_raw + S12_OFF + 512 + col * 4);
            v[e] = f2bf(sf * S1 + cf * S2);
        }
        const int dst = r * 256 + ((u16 * 16) ^ ((r & 7) << 4));
        *(ushort8v*)(lds_raw + dst) = v;
    } else if (tid < 400) {
        const int u16 = tid - 384, r = 175;
        const int dst = r * 256 + ((u16 * 16) ^ ((r & 7) << 4));
        *(ushort8v*)(lds_raw + dst) = (ushort8v)(unsigned short)0;
    }
    // Q converts overlap the barrier wait
    bf16x8 qf[4];
    #pragma unroll
    for (int kk = 0; kk < 4; ++kk)
        qf[kk] = __builtin_bit_cast(bf16x8, cvt8(qpf[2 * kk], qpf[2 * kk + 1]));

    __syncthreads();   // main barrier: K_ext complete

    // ---- phase 3: MFMA
    f32x4 acc[11];
    #pragma unroll
    for (int j = 0; j < 11; ++j) acc[j] = (f32x4)(0.f);

    #pragma unroll
    for (int kk = 0; kk < 4; ++kk) {
        #pragma unroll
        for (int j = 0; j < 11; ++j) {
            const int r = j * 16 + lr;
            const int byt = r * 256 + (((kk * 64) + (lk * 16)) ^ ((r & 7) << 4));
            bf16x8 bf = __builtin_bit_cast(bf16x8, *(const ushort8v*)(lds_raw + byt));
            acc[j] = __builtin_amdgcn_mfma_f32_16x16x32_bf16(qf[kk], bf, acc[j], 0, 0, 0);
        }
    }

    // ---- bd exchange (wave-private rows; redp/s12 dead, aliasing safe)
    {
        const int c9 = 144 + lr;              // tile 9: cols 144..159
        if (c9 >= C_) {
            const int f = c9 - C_;            // 0..8
            #pragma unroll
            for (int reg = 0; reg < 4; ++reg) {
                const int w = w0 + lk * 4 + reg;
                bd[w * BD_PITCH + f] = f2bf(acc[9][reg]);
            }
        }
        const int f10 = 9 + lr;               // tile 10: f = 9..23
        if (f10 < SPAN) {
            #pragma unroll
            for (int reg = 0; reg < 4; ++reg) {
                const int w = w0 + lk * 4 + reg;
                bd[w * BD_PITCH + f10] = f2bf(acc[10][reg]);
            }
        }
    }

    // ---- final write: out[w][c] = ac + (0 <= c-w < 24 ? bd[w][c-w] : 0)
    #pragma unroll
    for (int j = 0; j < 10; ++j) {
        const int c = j * 16 + lr;
        if (c < C_) {
            #pragma unroll
            for (int reg = 0; reg < 4; ++reg) {
                const int w = w0 + lk * 4 + reg;
                float v = acc[j][reg];
                const int d = c - w;
                if (d >= 0 && d < SPAN) v += bf2f(bd[w * BD_PITCH + d]);
                out[obase + (size_t)w * C_ + c] = v;
            }
        }
    }
}

extern "C" void kernel_launch(void* const* d_in, const int* in_sizes, int n_in,
                              void* d_out, int out_size, void* d_ws, size_t ws_size,
                              hipStream_t stream) {
    const float* queries = (const float*)d_in[0];
    const float* keys    = (const float*)d_in[1];
    const float* posproj = (const float*)d_in[2];
    float* out = (float*)d_out;

    float* part = (float*)d_ws;      // 64*1024 f32 = 256 KB

    SC sc;
    for (int f = 0; f < SPAN; ++f) {
        float p = (float)(11 - f);   // MAX_BACKWARD..-MAX_FORWARD
        sc.s[f] = sinf(p);
        sc.c[f] = cosf(p);
    }

    k_partial<<<64, 256, 0, stream>>>(posproj, part);
    k_main<<<1024, 512, 0, stream>>>(queries, keys, part, out, sc);
}

// Round 7
// 50.623 us; speedup vs baseline: 1.1831x; 1.0055x over previous
//
#include <hip/hip_runtime.h>
#include <cmath>

#define NHEADS 8
#define HDIM 128
#define SPAN 24
#define U_ 16
#define W_ 128
#define C_ 151
#define HID 1024

typedef unsigned short ushort8v __attribute__((ext_vector_type(8)));
typedef unsigned short ushort4v __attribute__((ext_vector_type(4)));
typedef __bf16 bf16x8 __attribute__((ext_vector_type(8)));
typedef float f32x4 __attribute__((ext_vector_type(4)));

__device__ inline unsigned short f2bf(float f) {
    union { float f; unsigned u; } v; v.f = f;
    unsigned r = v.u + 0x7FFFu + ((v.u >> 16) & 1u);
    return (unsigned short)(r >> 16);
}
__device__ inline float bf2f(unsigned short u) {
    union { unsigned u; float f; } v; v.u = ((unsigned)u) << 16;
    return v.f;
}
__device__ inline ushort8v cvt8(float4 a, float4 b) {
    ushort8v v;
    v[0] = f2bf(a.x); v[1] = f2bf(a.y); v[2] = f2bf(a.z); v[3] = f2bf(a.w);
    v[4] = f2bf(b.x); v[5] = f2bf(b.y); v[6] = f2bf(b.z); v[7] = f2bf(b.w);
    return v;
}

// ---- kernel 1: partial column sums of pos_proj (256 blocks x 64 thr) ----
__global__ void k_partial(const float* __restrict__ pp, float* __restrict__ part) {
    const int bi = blockIdx.x >> 2, cj = blockIdx.x & 3;
    const int col = cj * 256 + threadIdx.x * 4;
    const int row0 = bi * 16;
    float4 s = make_float4(0.f, 0.f, 0.f, 0.f);
    #pragma unroll
    for (int i = 0; i < 16; ++i) {
        float4 v = *(const float4*)(pp + (size_t)(row0 + i) * HID + col);
        s.x += v.x; s.y += v.y; s.z += v.z; s.w += v.w;
    }
    *(float4*)(part + (size_t)bi * HID + col) = s;
}

struct SC { float s[SPAN]; float c[SPAN]; };

// ---- main kernel: chunked double-buffered pipeline ----
// K_ext 176 rows split: chunks 0..4 = 32 rows, chunk 5 = 16 rows.
// LDS: buf0 [0,8192) buf1 [8192,16384) aux/bd [16384, 22784).
#define CHUNK_B 8192
#define AUX_OFF 16384
#define S12_OFF (AUX_OFF + 4096)
#define BD_PITCH 25

__device__ inline ushort8v emb8(const char* lds_raw, int f, int u16, const SC& sc) {
    float4 s1a = *(const float4*)(lds_raw + S12_OFF + u16 * 32);
    float4 s1b = *(const float4*)(lds_raw + S12_OFF + u16 * 32 + 16);
    float4 s2a = *(const float4*)(lds_raw + S12_OFF + 512 + u16 * 32);
    float4 s2b = *(const float4*)(lds_raw + S12_OFF + 512 + u16 * 32 + 16);
    const float sf = sc.s[f], cf = sc.c[f];
    ushort8v v;
    v[0] = f2bf(sf * s1a.x + cf * s2a.x); v[1] = f2bf(sf * s1a.y + cf * s2a.y);
    v[2] = f2bf(sf * s1a.z + cf * s2a.z); v[3] = f2bf(sf * s1a.w + cf * s2a.w);
    v[4] = f2bf(sf * s1b.x + cf * s2b.x); v[5] = f2bf(sf * s1b.y + cf * s2b.y);
    v[6] = f2bf(sf * s1b.z + cf * s2b.z); v[7] = f2bf(sf * s1b.w + cf * s2b.w);
    return v;
}

#define ISSUE_K(c, P0, P1)                                                     \
    {                                                                          \
        const int r_ = 32 * (c) + (tid >> 4);                                  \
        if (r_ < C_) {                                                         \
            const float* s_ = k + kbase + (size_t)r_ * HID + u16 * 8;          \
            P0 = *(const float4*)s_; P1 = *(const float4*)(s_ + 4);            \
        }                                                                      \
    }

// chunks 0..3: all rows are K rows (no branch)
#define WRITE_PURE(c, P0, P1, BUFOFF)                                          \
    {                                                                          \
        const int rl_ = tid >> 4;                                              \
        const int dst_ = (BUFOFF) + rl_ * 256 + ((u16 * 16) ^ ((rl_ & 7) << 4));\
        *(ushort8v*)(lds_raw + dst_) = cvt8(P0, P1);                           \
    }

// chunk 4: rows 128..150 are K, 151..159 are emb
#define WRITE_C4(P0, P1, BUFOFF)                                               \
    {                                                                          \
        const int rl_ = tid >> 4;                                              \
        const int r_ = 128 + rl_;                                              \
        const int dst_ = (BUFOFF) + rl_ * 256 + ((u16 * 16) ^ ((rl_ & 7) << 4));\
        ushort8v v_;                                                           \
        if (r_ < C_) v_ = cvt8(P0, P1);                                        \
        else         v_ = emb8(lds_raw, r_ - C_, u16, sc);                     \
        *(ushort8v*)(lds_raw + dst_) = v_;                                     \
    }

// chunk 5: rows 160..174 emb, 175 zero; only tid<256 participate
#define WRITE_C5(BUFOFF)                                                       \
    if (tid < 256) {                                                           \
        const int rl_ = tid >> 4;                                              \
        const int r_ = 160 + rl_;                                              \
        const int dst_ = (BUFOFF) + rl_ * 256 + ((u16 * 16) ^ ((rl_ & 7) << 4));\
        ushort8v v_;                                                           \
        if (r_ < 175) v_ = emb8(lds_raw, r_ - C_, u16, sc);                    \
        else          v_ = (ushort8v)(unsigned short)0;                        \
        *(ushort8v*)(lds_raw + dst_) = v_;                                     \
    }

#define MFMA2(c, BUFOFF)                                                       \
    {                                                                          \
        _Pragma("unroll")                                                      \
        for (int kk = 0; kk < 4; ++kk) {                                       \
            _Pragma("unroll")                                                  \
            for (int jj = 0; jj < 2; ++jj) {                                   \
                const int rl = jj * 16 + lr;                                   \
                const int byt = (BUFOFF) + rl * 256 +                          \
                                (((kk * 64) + (lk * 16)) ^ ((rl & 7) << 4));   \
                bf16x8 bf = __builtin_bit_cast(bf16x8,                         \
                                *(const ushort8v*)(lds_raw + byt));            \
                acc[2 * (c) + jj] = __builtin_amdgcn_mfma_f32_16x16x32_bf16(   \
                                        qf[kk], bf, acc[2 * (c) + jj], 0, 0, 0);\
            }                                                                  \
        }                                                                      \
    }

#define MFMA1(BUFOFF)                                                          \
    {                                                                          \
        _Pragma("unroll")                                                      \
        for (int kk = 0; kk < 4; ++kk) {                                       \
            const int rl = lr;                                                 \
            const int byt = (BUFOFF) + rl * 256 +                              \
                            (((kk * 64) + (lk * 16)) ^ ((rl & 7) << 4));       \
            bf16x8 bf = __builtin_bit_cast(bf16x8,                             \
                            *(const ushort8v*)(lds_raw + byt));                \
            acc[10] = __builtin_amdgcn_mfma_f32_16x16x32_bf16(                 \
                          qf[kk], bf, acc[10], 0, 0, 0);                       \
        }                                                                      \
    }

__global__ __launch_bounds__(512, 4) void k_main(const float* __restrict__ q,
                                                 const float* __restrict__ k,
                                                 const float* __restrict__ part,
                                                 float* __restrict__ out, SC sc) {
    __shared__ __align__(16) char lds_raw[AUX_OFF + W_ * BD_PITCH * 2];
    unsigned short* bd = (unsigned short*)(lds_raw + AUX_OFF);  // alias redp/s12

    const int bid = blockIdx.x;
    const int n = bid & 7;
    const int u = (bid >> 3) & 15;
    const int b = bid >> 7;

    const size_t qbase = ((size_t)(b * U_ + u) * W_) * HID + n * HDIM;
    const size_t kbase = ((size_t)(b * U_ + u) * C_) * HID + n * HDIM;
    const size_t obase = ((size_t)((b * NHEADS + n) * U_ + u)) * (W_ * C_);

    const int tid = threadIdx.x;
    const int lane = tid & 63;
    const int wave = tid >> 6;
    const int w0 = wave * 16;
    const int lr = lane & 15;
    const int lk = lane >> 4;
    const int u16 = tid & 15;

    // ---- prologue: issue pp4, chunk0->A, chunk1->B, Q loads
    const int c4 = tid & 31, rg = tid >> 5;
    float4 pp4[4];
    #pragma unroll
    for (int i = 0; i < 4; ++i)
        pp4[i] = *(const float4*)(part + (size_t)(rg * 4 + i) * HID + n * HDIM + c4 * 4);

    float4 a0, a1, b0, b1;
    ISSUE_K(0, a0, a1);
    ISSUE_K(1, b0, b1);

    const float* qrow = q + qbase + (size_t)(w0 + lr) * HID + lk * 8;
    float4 qpf[8];
    #pragma unroll
    for (int kk = 0; kk < 4; ++kk) {
        qpf[2 * kk]     = *(const float4*)(qrow + kk * 32);
        qpf[2 * kk + 1] = *(const float4*)(qrow + kk * 32 + 4);
    }

    // redp partial reduce + write (aux region)
    {
        float4 rs;
        rs.x = pp4[0].x + pp4[1].x + pp4[2].x + pp4[3].x;
        rs.y = pp4[0].y + pp4[1].y + pp4[2].y + pp4[3].y;
        rs.z = pp4[0].z + pp4[1].z + pp4[2].z + pp4[3].z;
        rs.w = pp4[0].w + pp4[1].w + pp4[2].w + pp4[3].w;
        ushort4v rb;
        rb[0] = f2bf(rs.x); rb[1] = f2bf(rs.y); rb[2] = f2bf(rs.z); rb[3] = f2bf(rs.w);
        *(ushort4v*)(lds_raw + AUX_OFF + rg * 256 + c4 * 8) = rb;
    }
    WRITE_PURE(0, a0, a1, 0);
    __syncthreads();   // A: redp + chunk0 ready

    // s12 reduce; Q convert overlaps
    if (tid < 256) {
        const int col = tid & 127, half = tid >> 7;
        float s = 0.f;
        #pragma unroll
        for (int g = 0; g < 8; ++g)
            s += bf2f(*(const unsigned short*)(lds_raw + AUX_OFF + (half * 8 + g) * 256 + col * 2));
        *(float*)(lds_raw + S12_OFF + (half * 128 + col) * 4) = s;
    }
    bf16x8 qf[4];
    #pragma unroll
    for (int kk = 0; kk < 4; ++kk)
        qf[kk] = __builtin_bit_cast(bf16x8, cvt8(qpf[2 * kk], qpf[2 * kk + 1]));

    f32x4 acc[11];
    #pragma unroll
    for (int j = 0; j < 11; ++j) acc[j] = (f32x4)(0.f);

    __syncthreads();   // B: s12 ready

    // ---- pipelined chunk loop (unrolled; chunk c in buf[c&1])
    WRITE_PURE(1, b0, b1, CHUNK_B);  ISSUE_K(2, a0, a1);  MFMA2(0, 0);
    __syncthreads();
    WRITE_PURE(2, a0, a1, 0);        ISSUE_K(3, b0, b1);  MFMA2(1, CHUNK_B);
    __syncthreads();
    WRITE_PURE(3, b0, b1, CHUNK_B);  ISSUE_K(4, a0, a1);  MFMA2(2, 0);
    __syncthreads();
    WRITE_C4(a0, a1, 0);                                  MFMA2(3, CHUNK_B);
    __syncthreads();
    WRITE_C5(CHUNK_B);                                    MFMA2(4, 0);
    __syncthreads();
    MFMA1(CHUNK_B);

    // ---- bd exchange (wave-private rows; aux dead, aliasing safe)
    {
        const int c9 = 144 + lr;
        if (c9 >= C_) {
            const int f = c9 - C_;
            #pragma unroll
            for (int reg = 0; reg < 4; ++reg) {
                const int w = w0 + lk * 4 + reg;
                bd[w * BD_PITCH + f] = f2bf(acc[9][reg]);
            }
        }
        const int f10 = 9 + lr;
        if (f10 < SPAN) {
            #pragma unroll
            for (int reg = 0; reg < 4; ++reg) {
                const int w = w0 + lk * 4 + reg;
                bd[w * BD_PITCH + f10] = f2bf(acc[10][reg]);
            }
        }
    }

    // ---- final write: out[w][c] = ac + (0 <= c-w < 24 ? bd[w][c-w] : 0)
    #pragma unroll
    for (int j = 0; j < 10; ++j) {
        const int c = j * 16 + lr;
        if (c < C_) {
            #pragma unroll
            for (int reg = 0; reg < 4; ++reg) {
                const int w = w0 + lk * 4 + reg;
                float v = acc[j][reg];
                const int d = c - w;
                if (d >= 0 && d < SPAN) v += bf2f(bd[w * BD_PITCH + d]);
                out[obase + (size_t)w * C_ + c] = v;
            }
        }
    }
}

extern "C" void kernel_launch(void* const* d_in, const int* in_sizes, int n_in,
                              void* d_out, int out_size, void* d_ws, size_t ws_size,
                              hipStream_t stream) {
    const float* queries = (const float*)d_in[0];
    const float* keys    = (const float*)d_in[1];
    const float* posproj = (const float*)d_in[2];
    float* out = (float*)d_out;

    float* part = (float*)d_ws;      // 64*1024 f32 = 256 KB

    SC sc;
    for (int f = 0; f < SPAN; ++f) {
        float p = (float)(11 - f);   // MAX_BACKWARD..-MAX_FORWARD
        sc.s[f] = sinf(p);
        sc.c[f] = cosf(p);
    }

    k_partial<<<256, 64, 0, stream>>>(posproj, part);
    k_main<<<1024, 512, 0, stream>>>(queries, keys, part, out, sc);
}

// Round 8
// 49.429 us; speedup vs baseline: 1.2117x; 1.0242x over previous
//
#include <hip/hip_runtime.h>
#include <cmath>

#define NHEADS 8
#define HDIM 128
#define SPAN 24
#define U_ 16
#define W_ 128
#define C_ 151
#define HID 1024

typedef unsigned short ushort8v __attribute__((ext_vector_type(8)));
typedef unsigned short ushort4v __attribute__((ext_vector_type(4)));
typedef __bf16 bf16x8 __attribute__((ext_vector_type(8)));
typedef float f32x4 __attribute__((ext_vector_type(4)));

__device__ inline unsigned short f2bf(float f) {
    union { float f; unsigned u; } v; v.f = f;
    unsigned r = v.u + 0x7FFFu + ((v.u >> 16) & 1u);
    return (unsigned short)(r >> 16);
}
__device__ inline float bf2f(unsigned short u) {
    union { unsigned u; float f; } v; v.u = ((unsigned)u) << 16;
    return v.f;
}
__device__ inline ushort8v cvt8(float4 a, float4 b) {
    ushort8v v;
    v[0] = f2bf(a.x); v[1] = f2bf(a.y); v[2] = f2bf(a.z); v[3] = f2bf(a.w);
    v[4] = f2bf(b.x); v[5] = f2bf(b.y); v[6] = f2bf(b.z); v[7] = f2bf(b.w);
    return v;
}

// lgkm-only barrier: orders LDS producer->consumer across waves WITHOUT
// draining vmcnt (global loads/stores stay in flight across it).
#define BAR() asm volatile("s_waitcnt lgkmcnt(0)\n\ts_barrier" ::: "memory")

// ---- kernel 1: partial column sums of pos_proj (256 blocks x 64 thr) ----
__global__ void k_partial(const float* __restrict__ pp, float* __restrict__ part) {
    const int bi = blockIdx.x >> 2, cj = blockIdx.x & 3;
    const int col = cj * 256 + threadIdx.x * 4;
    const int row0 = bi * 16;
    float4 s = make_float4(0.f, 0.f, 0.f, 0.f);
    #pragma unroll
    for (int i = 0; i < 16; ++i) {
        float4 v = *(const float4*)(pp + (size_t)(row0 + i) * HID + col);
        s.x += v.x; s.y += v.y; s.z += v.z; s.w += v.w;
    }
    *(float4*)(part + (size_t)bi * HID + col) = s;
}

struct SC { float s[SPAN]; float c[SPAN]; };

// ---- main kernel: chunked dbuf pipeline, chunk order [4,5,0,1,2,3],
// lgkm-only barriers (loads never drained), stores streamed into the loop.
// LDS: buf0 [0,8192) buf1 [8192,16384) aux/bd [16384, 22784).
#define CHUNK_B 8192
#define AUX_OFF 16384
#define S12_OFF (AUX_OFF + 4096)
#define BD_PITCH 25

__device__ inline ushort8v emb8(const char* lds_raw, int f, int u16, const SC& sc) {
    float4 s1a = *(const float4*)(lds_raw + S12_OFF + u16 * 32);
    float4 s1b = *(const float4*)(lds_raw + S12_OFF + u16 * 32 + 16);
    float4 s2a = *(const float4*)(lds_raw + S12_OFF + 512 + u16 * 32);
    float4 s2b = *(const float4*)(lds_raw + S12_OFF + 512 + u16 * 32 + 16);
    const float sf = sc.s[f], cf = sc.c[f];
    ushort8v v;
    v[0] = f2bf(sf * s1a.x + cf * s2a.x); v[1] = f2bf(sf * s1a.y + cf * s2a.y);
    v[2] = f2bf(sf * s1a.z + cf * s2a.z); v[3] = f2bf(sf * s1a.w + cf * s2a.w);
    v[4] = f2bf(sf * s1b.x + cf * s2b.x); v[5] = f2bf(sf * s1b.y + cf * s2b.y);
    v[6] = f2bf(sf * s1b.z + cf * s2b.z); v[7] = f2bf(sf * s1b.w + cf * s2b.w);
    return v;
}

#define ISSUE_K(c, P0, P1)                                                     \
    {                                                                          \
        const int r_ = 32 * (c) + (tid >> 4);                                  \
        if (r_ < C_) {                                                         \
            const float* s_ = k + kbase + (size_t)r_ * HID + u16 * 8;          \
            P0 = *(const float4*)s_; P1 = *(const float4*)(s_ + 4);            \
        }                                                                      \
    }

#define WRITE_PURE(P0, P1, BUFOFF)                                             \
    {                                                                          \
        const int rl_ = tid >> 4;                                              \
        const int dst_ = (BUFOFF) + rl_ * 256 + ((u16 * 16) ^ ((rl_ & 7) << 4));\
        *(ushort8v*)(lds_raw + dst_) = cvt8(P0, P1);                           \
    }

// chunk 4: rows 128..150 are K, 151..159 are emb
#define WRITE_C4(P0, P1, BUFOFF)                                               \
    {                                                                          \
        const int rl_ = tid >> 4;                                              \
        const int r_ = 128 + rl_;                                              \
        const int dst_ = (BUFOFF) + rl_ * 256 + ((u16 * 16) ^ ((rl_ & 7) << 4));\
        ushort8v v_;                                                           \
        if (r_ < C_) v_ = cvt8(P0, P1);                                        \
        else         v_ = emb8(lds_raw, r_ - C_, u16, sc);                     \
        *(ushort8v*)(lds_raw + dst_) = v_;                                     \
    }

// chunk 5: rows 160..174 emb, 175 zero; only tid<256 (no global data at all)
#define WRITE_C5(BUFOFF)                                                       \
    if (tid < 256) {                                                           \
        const int rl_ = tid >> 4;                                              \
        const int r_ = 160 + rl_;                                              \
        const int dst_ = (BUFOFF) + rl_ * 256 + ((u16 * 16) ^ ((rl_ & 7) << 4));\
        ushort8v v_;                                                           \
        if (r_ < 175) v_ = emb8(lds_raw, r_ - C_, u16, sc);                    \
        else          v_ = (ushort8v)(unsigned short)0;                        \
        *(ushort8v*)(lds_raw + dst_) = v_;                                     \
    }

#define MFMA2(c, BUFOFF)                                                       \
    {                                                                          \
        _Pragma("unroll")                                                      \
        for (int kk = 0; kk < 4; ++kk) {                                       \
            _Pragma("unroll")                                                  \
            for (int jj = 0; jj < 2; ++jj) {                                   \
                const int rl = jj * 16 + lr;                                   \
                const int byt = (BUFOFF) + rl * 256 +                          \
                                (((kk * 64) + (lk * 16)) ^ ((rl & 7) << 4));   \
                bf16x8 bf = __builtin_bit_cast(bf16x8,                         \
                                *(const ushort8v*)(lds_raw + byt));            \
                acc[2 * (c) + jj] = __builtin_amdgcn_mfma_f32_16x16x32_bf16(   \
                                        qf[kk], bf, acc[2 * (c) + jj], 0, 0, 0);\
            }                                                                  \
        }                                                                      \
    }

#define MFMA1(BUFOFF)                                                          \
    {                                                                          \
        _Pragma("unroll")                                                      \
        for (int kk = 0; kk < 4; ++kk) {                                       \
            const int rl = lr;                                                 \
            const int byt = (BUFOFF) + rl * 256 +                              \
                            (((kk * 64) + (lk * 16)) ^ ((rl & 7) << 4));       \
            bf16x8 bf = __builtin_bit_cast(bf16x8,                             \
                            *(const ushort8v*)(lds_raw + byt));                \
            acc[10] = __builtin_amdgcn_mfma_f32_16x16x32_bf16(                 \
                          qf[kk], bf, acc[10], 0, 0, 0);                       \
        }                                                                      \
    }

#define STORE_TILE(J)                                                          \
    {                                                                          \
        const int c_ = (J) * 16 + lr;                                          \
        if (c_ < C_) {                                                         \
            _Pragma("unroll")                                                  \
            for (int reg = 0; reg < 4; ++reg) {                                \
                const int w_ = w0 + lk * 4 + reg;                              \
                float v_ = acc[J][reg];                                        \
                const int d_ = c_ - w_;                                        \
                if (d_ >= 0 && d_ < SPAN) v_ += bf2f(bd[w_ * BD_PITCH + d_]);  \
                out[obase + (size_t)w_ * C_ + c_] = v_;                        \
            }                                                                  \
        }                                                                      \
    }

__global__ __launch_bounds__(512, 4) void k_main(const float* __restrict__ q,
                                                 const float* __restrict__ k,
                                                 const float* __restrict__ part,
                                                 float* __restrict__ out, SC sc) {
    __shared__ __align__(16) char lds_raw[AUX_OFF + W_ * BD_PITCH * 2];
    unsigned short* bd = (unsigned short*)(lds_raw + AUX_OFF);  // alias redp/s12

    const int bid = blockIdx.x;
    const int n = bid & 7;
    const int u = (bid >> 3) & 15;
    const int b = bid >> 7;

    const size_t qbase = ((size_t)(b * U_ + u) * W_) * HID + n * HDIM;
    const size_t kbase = ((size_t)(b * U_ + u) * C_) * HID + n * HDIM;
    const size_t obase = ((size_t)((b * NHEADS + n) * U_ + u)) * (W_ * C_);

    const int tid = threadIdx.x;
    const int lane = tid & 63;
    const int wave = tid >> 6;
    const int w0 = wave * 16;
    const int lr = lane & 15;
    const int lk = lane >> 4;
    const int u16 = tid & 15;

    // ---- prologue: issue pp4, Q, chunk4, chunk0 loads (in this age order)
    const int c4 = tid & 31, rg = tid >> 5;
    float4 pp4[4];
    #pragma unroll
    for (int i = 0; i < 4; ++i)
        pp4[i] = *(const float4*)(part + (size_t)(rg * 4 + i) * HID + n * HDIM + c4 * 4);

    const float* qrow = q + qbase + (size_t)(w0 + lr) * HID + lk * 8;
    float4 qpf[8];
    #pragma unroll
    for (int kk = 0; kk < 4; ++kk) {
        qpf[2 * kk]     = *(const float4*)(qrow + kk * 32);
        qpf[2 * kk + 1] = *(const float4*)(qrow + kk * 32 + 4);
    }

    float4 a0, a1, b0, b1;
    ISSUE_K(4, a0, a1);     // rows 128..150 predicated
    ISSUE_K(0, b0, b1);

    // redp partial reduce + LDS write
    {
        float4 rs;
        rs.x = pp4[0].x + pp4[1].x + pp4[2].x + pp4[3].x;
        rs.y = pp4[0].y + pp4[1].y + pp4[2].y + pp4[3].y;
        rs.z = pp4[0].z + pp4[1].z + pp4[2].z + pp4[3].z;
        rs.w = pp4[0].w + pp4[1].w + pp4[2].w + pp4[3].w;
        ushort4v rb;
        rb[0] = f2bf(rs.x); rb[1] = f2bf(rs.y); rb[2] = f2bf(rs.z); rb[3] = f2bf(rs.w);
        *(ushort4v*)(lds_raw + AUX_OFF + rg * 256 + c4 * 8) = rb;
    }
    BAR();   // redp ready (global loads stay in flight)

    // s12 reduce; Q convert overlaps
    if (tid < 256) {
        const int col = tid & 127, half = tid >> 7;
        float s = 0.f;
        #pragma unroll
        for (int g = 0; g < 8; ++g)
            s += bf2f(*(const unsigned short*)(lds_raw + AUX_OFF + (half * 8 + g) * 256 + col * 2));
        *(float*)(lds_raw + S12_OFF + (half * 128 + col) * 4) = s;
    }
    bf16x8 qf[4];
    #pragma unroll
    for (int kk = 0; kk < 4; ++kk)
        qf[kk] = __builtin_bit_cast(bf16x8, cvt8(qpf[2 * kk], qpf[2 * kk + 1]));

    f32x4 acc[11];
    #pragma unroll
    for (int j = 0; j < 11; ++j) acc[j] = (f32x4)(0.f);

    BAR();   // s12 ready

    // ---- pre-loop: stage chunk4 (K rows 128..150 + emb 151..159) -> buf0
    WRITE_C4(a0, a1, 0);
    BAR();

    // P0: MFMA ch4; stage ch5 -> buf1 (emb only); issue ch1
    MFMA2(4, 0);
    WRITE_C5(CHUNK_B);
    ISSUE_K(1, a0, a1);
    BAR();

    // P1: MFMA ch5; bd exchange (wave-private, aux now dead); stage ch0 -> buf0; issue ch2
    MFMA1(CHUNK_B);
    {
        const int c9 = 144 + lr;
        if (c9 >= C_) {
            const int f = c9 - C_;
            #pragma unroll
            for (int reg = 0; reg < 4; ++reg) {
                const int w = w0 + lk * 4 + reg;
                bd[w * BD_PITCH + f] = f2bf(acc[9][reg]);
            }
        }
        const int f10 = 9 + lr;
        if (f10 < SPAN) {
            #pragma unroll
            for (int reg = 0; reg < 4; ++reg) {
                const int w = w0 + lk * 4 + reg;
                bd[w * BD_PITCH + f10] = f2bf(acc[10][reg]);
            }
        }
    }
    WRITE_PURE(b0, b1, 0);
    ISSUE_K(2, b0, b1);
    BAR();

    // P2: MFMA ch0; stage ch1 -> buf1; issue ch3; store tiles 8,9
    MFMA2(0, 0);
    WRITE_PURE(a0, a1, CHUNK_B);
    ISSUE_K(3, a0, a1);
    STORE_TILE(8);
    STORE_TILE(9);
    BAR();

    // P3: MFMA ch1; stage ch2 -> buf0; store tiles 0,1
    MFMA2(1, CHUNK_B);
    WRITE_PURE(b0, b1, 0);
    STORE_TILE(0);
    STORE_TILE(1);
    BAR();

    // P4: MFMA ch2; stage ch3 -> buf1; store tiles 2,3
    MFMA2(2, 0);
    WRITE_PURE(a0, a1, CHUNK_B);
    STORE_TILE(2);
    STORE_TILE(3);
    BAR();

    // P5: MFMA ch3; store tiles 4,5 (no further LDS writes -> no barrier)
    MFMA2(3, CHUNK_B);
    STORE_TILE(4);
    STORE_TILE(5);

    // epilogue
    STORE_TILE(6);
    STORE_TILE(7);
}

extern "C" void kernel_launch(void* const* d_in, const int* in_sizes, int n_in,
                              void* d_out, int out_size, void* d_ws, size_t ws_size,
                              hipStream_t stream) {
    const float* queries = (const float*)d_in[0];
    const float* keys    = (const float*)d_in[1];
    const float* posproj = (const float*)d_in[2];
    float* out = (float*)d_out;

    float* part = (float*)d_ws;      // 64*1024 f32 = 256 KB

    SC sc;
    for (int f = 0; f < SPAN; ++f) {
        float p = (float)(11 - f);   // MAX_BACKWARD..-MAX_FORWARD
        sc.s[f] = sinf(p);
        sc.c[f] = cosf(p);
    }

    k_partial<<<256, 64, 0, stream>>>(posproj, part);
    k_main<<<1024, 512, 0, stream>>>(queries, keys, part, out, sc);
}